// Round 9
// baseline (247.659 us; speedup 1.0000x reference)
//
#include <hip/hip_runtime.h>

#define N_NODES 50000
#define N_EDGES 800000
#define D 64
#define NBUCKETS 196          // dst>>8, 0..195
#define CBLOCKS 256
#define CHUNK (N_EDGES / CBLOCKS)   // 3125

// bf16 helpers (RNE), bit-level.
__device__ __forceinline__ unsigned short f2bf(float f) {
    unsigned u = __float_as_uint(f);
    return (unsigned short)((u + 0x7fffu + ((u >> 16) & 1u)) >> 16);
}
__device__ __forceinline__ float bflo(unsigned u) {
    return __uint_as_float(u << 16);
}
__device__ __forceinline__ float bfhi(unsigned u) {
    return __uint_as_float(u & 0xffff0000u);
}

// ---------- CSR build (identical to the R6/R8 passing version) --------------
__global__ void __launch_bounds__(256) count_kernel(
    const int* __restrict__ dst, int* __restrict__ bucketCnt) {
    __shared__ int hist[256];
    int t = threadIdx.x;
    hist[t] = 0;
    __syncthreads();
    int lo = blockIdx.x * CHUNK, hi = lo + CHUNK;
    for (int i = lo + t; i < hi; i += 256)
        atomicAdd(&hist[dst[i] >> 8], 1);
    __syncthreads();
    if (hist[t] > 0) atomicAdd(&bucketCnt[t], hist[t]);
}

__global__ void __launch_bounds__(256) scan_kernel(
    const int* __restrict__ bucketCnt, int* __restrict__ bucketBase,
    int* __restrict__ cursorPad) {
    __shared__ int s[256];
    int t = threadIdx.x;
    int v = bucketCnt[t];
    s[t] = v;
    __syncthreads();
#pragma unroll
    for (int d = 1; d < 256; d <<= 1) {
        int u = (t >= d) ? s[t - d] : 0;
        __syncthreads();
        s[t] += u;
        __syncthreads();
    }
    int excl = s[t] - v;
    bucketBase[t] = excl;
    cursorPad[t * 16] = excl;
    if (t == 255) bucketBase[256] = s[255];
}

__global__ void __launch_bounds__(256) scatter_kernel(
    const int* __restrict__ src, const int* __restrict__ dst,
    int* __restrict__ cursorPad, int* __restrict__ staged) {
    __shared__ int hist[256];
    __shared__ int curs[256];
    int t = threadIdx.x;
    hist[t] = 0;
    __syncthreads();
    int lo = blockIdx.x * CHUNK, hi = lo + CHUNK;
    for (int i = lo + t; i < hi; i += 256)
        atomicAdd(&hist[dst[i] >> 8], 1);
    __syncthreads();
    if (hist[t] > 0) curs[t] = atomicAdd(&cursorPad[t * 16], hist[t]);
    __syncthreads();
    for (int i = lo + t; i < hi; i += 256) {
        int d = dst[i];
        int b = d >> 8;
        int pos = atomicAdd(&curs[b], 1);
        staged[pos] = (src[i] << 8) | (d & 255);
    }
}

__global__ void __launch_bounds__(256) csr_build_kernel(
    const int* __restrict__ bucketBase, const int* __restrict__ staged,
    int* __restrict__ csr, int* __restrict__ startA, int* __restrict__ endA) {
    __shared__ int deg[256];
    __shared__ int sc[256];
    __shared__ int curs[256];
    int k = blockIdx.x;
    int t = threadIdx.x;
    int base = bucketBase[k];
    int cnt  = bucketBase[k + 1] - base;
    deg[t] = 0;
    __syncthreads();
    for (int i = t; i < cnt; i += 256)
        atomicAdd(&deg[staged[base + i] & 255], 1);
    __syncthreads();
    int v = deg[t];
    sc[t] = v;
    __syncthreads();
#pragma unroll
    for (int d = 1; d < 256; d <<= 1) {
        int u = (t >= d) ? sc[t - d] : 0;
        __syncthreads();
        sc[t] += u;
        __syncthreads();
    }
    int start = sc[t] - v;
    int node = k * 256 + t;
    if (node < N_NODES) {
        startA[node] = base + start;
        endA[node]   = base + start + v;
    }
    curs[t] = start;
    __syncthreads();
    for (int i = t; i < cnt; i += 256) {
        int e = staged[base + i];
        int pos = atomicAdd(&curs[e & 255], 1);
        csr[base + pos] = e >> 8;
    }
}

// ---------- Cast x -> two bf16 half-feature tables (each 3.2 MB, L2-fits) ---
__global__ void __launch_bounds__(256) cast_split(
    const float* __restrict__ X, unsigned* __restrict__ Xlo,
    unsigned* __restrict__ Xhi) {
    int t = blockIdx.x * 256 + threadIdx.x;   // over N*32 feature-pairs
    int node = t >> 5, rem = t & 31;
    float2 v = ((const float2*)X)[node * 32 + rem];   // feats 2rem, 2rem+1
    unsigned u = (unsigned)f2bf(v.x) | ((unsigned)f2bf(v.y) << 16);
    if (rem < 16) Xlo[node * 16 + rem] = u;
    else          Xhi[node * 16 + (rem - 16)] = u;
}

// ---------- Gather over one 32-feature half (64 B rows, L2-resident) --------
// One wave per node; 16 lanes x 4 B per edge, 4 edges in parallel.
// All __shfl exec-uniform (clamped source in tail) -- the R5 lesson.
__global__ void __launch_bounds__(256) gather_half(
    const unsigned* __restrict__ Xh,   // [N][16] uints = 32 bf16
    const int* __restrict__ startA, const int* __restrict__ endA,
    const int* __restrict__ csr, float* __restrict__ agg, int halfOfs) {
    int tid = threadIdx.x;
    int wave = tid >> 6, lane = tid & 63;
    int node = blockIdx.x * 4 + wave;
    int sub = lane >> 4, fq = lane & 15;
    int j0 = startA[node], je = endA[node];
    float a0 = 0.f, a1 = 0.f;
    for (int jb = j0; jb < je; jb += 64) {          // je wave-uniform
        int idx = jb + lane;
        int p = csr[idx < je ? idx : (je - 1)];     // coalesced index batch
        int m = min(64, je - jb);                   // wave-uniform
        int b = 0;
        for (; b + 16 <= m; b += 16) {
            int i0 = __shfl(p, b + sub, 64);
            int i1 = __shfl(p, b + 4 + sub, 64);
            int i2 = __shfl(p, b + 8 + sub, 64);
            int i3 = __shfl(p, b + 12 + sub, 64);
            unsigned u0 = Xh[i0 * 16 + fq];
            unsigned u1 = Xh[i1 * 16 + fq];
            unsigned u2 = Xh[i2 * 16 + fq];
            unsigned u3 = Xh[i3 * 16 + fq];
            a0 += bflo(u0) + bflo(u1) + bflo(u2) + bflo(u3);
            a1 += bfhi(u0) + bfhi(u1) + bfhi(u2) + bfhi(u3);
        }
        for (; b < m; b += 4) {                     // uniform condition
            int sidx = b + sub;
            int scl = sidx < m ? sidx : (m - 1);    // active source lane
            int i0 = __shfl(p, scl, 64);            // executed by ALL lanes
            if (sidx < m) {                         // divergence only here
                unsigned u = Xh[i0 * 16 + fq];
                a0 += bflo(u);
                a1 += bfhi(u);
            }
        }
    }
#pragma unroll
    for (int mk = 16; mk <= 32; mk <<= 1) {
        a0 += __shfl_xor(a0, mk, 64);
        a1 += __shfl_xor(a1, mk, 64);
    }
    if (sub == 0)
        *(float2*)(agg + (size_t)node * D + halfOfs + fq * 2) =
            make_float2(a0, a1);
}

// ---------- Register-blocked dual GEMM (+ optional bf16 half-writes) --------
template<int RELU, int WBF>
__global__ void __launch_bounds__(256) dual_gemm(
    const float* __restrict__ X, const float* __restrict__ A,
    const float* __restrict__ Wr, const float* __restrict__ Wn,
    const float* __restrict__ bias, float* __restrict__ out,
    unsigned* __restrict__ Hlo, unsigned* __restrict__ Hhi) {
    __shared__ float sXT[D][D];
    __shared__ float sAT[D][D];
    __shared__ float sWr[D][D];
    __shared__ float sWn[D][D];

    int tid = threadIdx.x;
    int node0 = blockIdx.x * 64;

#pragma unroll
    for (int i = 0; i < 4; i++) {
        int idx = tid + 256 * i;
        ((float4*)sWr)[idx] = ((const float4*)Wr)[idx];
        ((float4*)sWn)[idx] = ((const float4*)Wn)[idx];
    }
    const float4* X4 = (const float4*)X;
    const float4* A4 = (const float4*)A;
    int nd = tid & 63;
    int gn = min(node0 + nd, N_NODES - 1);
#pragma unroll
    for (int pass = 0; pass < 4; pass++) {
        int kq = (tid >> 6) + pass * 4;
        float4 v = X4[gn * 16 + kq];
        float4 w = A4[gn * 16 + kq];
        sXT[kq * 4 + 0][nd] = v.x; sXT[kq * 4 + 1][nd] = v.y;
        sXT[kq * 4 + 2][nd] = v.z; sXT[kq * 4 + 3][nd] = v.w;
        sAT[kq * 4 + 0][nd] = w.x; sAT[kq * 4 + 1][nd] = w.y;
        sAT[kq * 4 + 2][nd] = w.z; sAT[kq * 4 + 3][nd] = w.w;
    }
    __syncthreads();

    int nq = tid >> 4;
    int cq = tid & 15;
    float4 b4 = ((const float4*)bias)[cq];
    float acc[4][4];
#pragma unroll
    for (int i = 0; i < 4; i++) {
        acc[i][0] = b4.x; acc[i][1] = b4.y; acc[i][2] = b4.z; acc[i][3] = b4.w;
    }

#pragma unroll 16
    for (int k = 0; k < D; k++) {
        float4 xv = *(const float4*)&sXT[k][nq * 4];
        float4 av = *(const float4*)&sAT[k][nq * 4];
        float4 wr = *(const float4*)&sWr[k][cq * 4];
        float4 wn = *(const float4*)&sWn[k][cq * 4];
        float xs[4] = {xv.x, xv.y, xv.z, xv.w};
        float as[4] = {av.x, av.y, av.z, av.w};
        float rs[4] = {wr.x, wr.y, wr.z, wr.w};
        float ns[4] = {wn.x, wn.y, wn.z, wn.w};
#pragma unroll
        for (int i = 0; i < 4; i++)
#pragma unroll
            for (int jj = 0; jj < 4; jj++) {
                acc[i][jj] = fmaf(xs[i], rs[jj], acc[i][jj]);
                acc[i][jj] = fmaf(as[i], ns[jj], acc[i][jj]);
            }
    }

    float4* out4 = (float4*)out;
#pragma unroll
    for (int i = 0; i < 4; i++) {
        int node = node0 + nq * 4 + i;
        if (node < N_NODES) {
            float4 r;
            r.x = acc[i][0]; r.y = acc[i][1]; r.z = acc[i][2]; r.w = acc[i][3];
            if (RELU) {
                r.x = fmaxf(r.x, 0.f); r.y = fmaxf(r.y, 0.f);
                r.z = fmaxf(r.z, 0.f); r.w = fmaxf(r.w, 0.f);
            }
            out4[node * 16 + cq] = r;
            if (WBF) {
                // cols 4cq..4cq+3 -> uint pair (2 bf16 each)
                unsigned ua = (unsigned)f2bf(r.x) | ((unsigned)f2bf(r.y) << 16);
                unsigned ub = (unsigned)f2bf(r.z) | ((unsigned)f2bf(r.w) << 16);
                uint2 up; up.x = ua; up.y = ub;
                if (cq < 8) ((uint2*)Hlo)[node * 8 + cq] = up;
                else        ((uint2*)Hhi)[node * 8 + (cq - 8)] = up;
            }
        }
    }
}

// ---------- launch ----------------------------------------------------------
extern "C" void kernel_launch(void* const* d_in, const int* in_sizes, int n_in,
                              void* d_out, int out_size, void* d_ws, size_t ws_size,
                              hipStream_t stream) {
    const float* x   = (const float*)d_in[0];
    const int*   edg = (const int*)d_in[1];
    const float* W1r = (const float*)d_in[2];
    const float* W1n = (const float*)d_in[3];
    const float* b1  = (const float*)d_in[4];
    const float* W2r = (const float*)d_in[5];
    const float* W2n = (const float*)d_in[6];
    const float* b2  = (const float*)d_in[7];
    float* out = (float*)d_out;

    const int* src = edg;
    const int* dst = edg + N_EDGES;

    // ws (256 MiB available) — generous non-overlapping layout.
    int* W           = (int*)d_ws;
    int* bucketCnt   = W;            // 256
    int* bucketBase  = W + 256;      // 257
    int* cursorPad   = W + 1024;     // 4096
    int* staged      = W + 8192;     // E
    int* csr         = staged + N_EDGES;
    int* startA      = csr + N_EDGES;
    int* endA        = startA + N_NODES;
    float* agg       = (float*)(endA + N_NODES);          // N*D f32
    unsigned* Xlo    = (unsigned*)(agg + (size_t)N_NODES * D);  // N*16 uints
    unsigned* Xhi    = Xlo + (size_t)N_NODES * 16;
    unsigned* Hlo    = Xhi + (size_t)N_NODES * 16;
    unsigned* Hhi    = Hlo + (size_t)N_NODES * 16;
    float* h         = out;          // layer-1 fp32 activations in d_out

    hipMemsetAsync(bucketCnt, 0, 256 * sizeof(int), stream);
    count_kernel<<<CBLOCKS, 256, 0, stream>>>(dst, bucketCnt);
    scan_kernel<<<1, 256, 0, stream>>>(bucketCnt, bucketBase, cursorPad);
    scatter_kernel<<<CBLOCKS, 256, 0, stream>>>(src, dst, cursorPad, staged);
    csr_build_kernel<<<NBUCKETS, 256, 0, stream>>>(bucketBase, staged, csr,
                                                   startA, endA);
    cast_split<<<(N_NODES * 32) / 256, 256, 0, stream>>>(x, Xlo, Xhi);

    const int GB = N_NODES / 4;          // 12500
    const int MB = (N_NODES + 63) / 64;  // 782

    // Layer 1: two half-feature gathers (each table 3.2 MB -> L2-resident)
    gather_half<<<GB, 256, 0, stream>>>(Xlo, startA, endA, csr, agg, 0);
    gather_half<<<GB, 256, 0, stream>>>(Xhi, startA, endA, csr, agg, 32);
    dual_gemm<1, 1><<<MB, 256, 0, stream>>>(x, agg, W1r, W1n, b1, h, Hlo, Hhi);
    // Layer 2
    gather_half<<<GB, 256, 0, stream>>>(Hlo, startA, endA, csr, agg, 0);
    gather_half<<<GB, 256, 0, stream>>>(Hhi, startA, endA, csr, agg, 32);
    dual_gemm<0, 0><<<MB, 256, 0, stream>>>(h, agg, W2r, W2n, b2, out,
                                            (unsigned*)0, (unsigned*)0);
}

// Round 10
// 203.591 us; speedup vs baseline: 1.2165x; 1.2165x over previous
//
#include <hip/hip_runtime.h>

#define N_NODES 50000
#define N_EDGES 800000
#define D 64
#define NBUCKETS 196          // dst>>8, 0..195
#define BCAP 8192             // fixed bucket capacity (Poisson(4082), 5sigma<4400)
#define SBLOCKS 256           // scatter blocks
#define CHUNK (N_EDGES / SBLOCKS)   // 3125
#define CASTBLOCKS 3125       // N*D/4 ushort4 items / 256 threads

// bf16 helpers (RNE), bit-level.
__device__ __forceinline__ unsigned short f2bf(float f) {
    unsigned u = __float_as_uint(f);
    return (unsigned short)((u + 0x7fffu + ((u >> 16) & 1u)) >> 16);
}
__device__ __forceinline__ float bflo(unsigned u) {
    return __uint_as_float(u << 16);
}
__device__ __forceinline__ float bfhi(unsigned u) {
    return __uint_as_float(u & 0xffff0000u);
}

// ---------- Scatter into fixed-capacity buckets + fused x->bf16 cast --------
// Blocks [0,256): scatter packed (src<<8 | dst&255) into bucket dst>>8.
// Blocks [256, 256+3125): cast x to bf16 (ushort4 per thread).
__global__ void __launch_bounds__(256) scatter_cast_kernel(
    const int* __restrict__ src, const int* __restrict__ dst,
    const float* __restrict__ X,
    int* __restrict__ cursorPad, int* __restrict__ staged,
    unsigned short* __restrict__ Xbf) {
    int t = threadIdx.x;
    if (blockIdx.x >= SBLOCKS) {
        int i = (blockIdx.x - SBLOCKS) * 256 + t;   // over N*D/4
        float4 v = ((const float4*)X)[i];
        ushort4 r;
        r.x = f2bf(v.x); r.y = f2bf(v.y); r.z = f2bf(v.z); r.w = f2bf(v.w);
        ((ushort4*)Xbf)[i] = r;
        return;
    }
    __shared__ int hist[256];
    __shared__ int curs[256];
    hist[t] = 0;
    __syncthreads();
    int lo = blockIdx.x * CHUNK, hi = lo + CHUNK;
    for (int i = lo + t; i < hi; i += 256)
        atomicAdd(&hist[dst[i] >> 8], 1);
    __syncthreads();
    // Reserve a contiguous chunk in bucket t's padded region.
    if (hist[t] > 0)
        curs[t] = t * BCAP + atomicAdd(&cursorPad[t * 16], hist[t]);
    __syncthreads();
    for (int i = lo + t; i < hi; i += 256) {
        int d = dst[i];
        int b = d >> 8;
        int pos = atomicAdd(&curs[b], 1);
        staged[pos] = (src[i] << 8) | (d & 255);
    }
}

// ---------- Per-bucket CSR build (padded regions; LDS scan + cursors) -------
__global__ void __launch_bounds__(256) csr_build_kernel(
    const int* __restrict__ cursorPad, const int* __restrict__ staged,
    int* __restrict__ csr, int* __restrict__ startA, int* __restrict__ endA) {
    __shared__ int deg[256];
    __shared__ int sc[256];
    __shared__ int curs[256];
    int k = blockIdx.x;
    int t = threadIdx.x;
    int base = k * BCAP;
    int cnt  = cursorPad[k * 16];          // edges landed in this bucket
    deg[t] = 0;
    __syncthreads();
    for (int i = t; i < cnt; i += 256)
        atomicAdd(&deg[staged[base + i] & 255], 1);
    __syncthreads();
    int v = deg[t];
    sc[t] = v;
    __syncthreads();
#pragma unroll
    for (int d = 1; d < 256; d <<= 1) {
        int u = (t >= d) ? sc[t - d] : 0;
        __syncthreads();
        sc[t] += u;
        __syncthreads();
    }
    int start = sc[t] - v;
    int node = k * 256 + t;
    if (node < N_NODES) {
        startA[node] = base + start;
        endA[node]   = base + start + v;
    }
    curs[t] = start;
    __syncthreads();
    for (int i = t; i < cnt; i += 256) {
        int e = staged[base + i];
        int pos = atomicAdd(&curs[e & 255], 1);
        csr[base + pos] = e >> 8;
    }
}

// ---------- Gather (bf16 rows): agg[n] = sum_{j in in(n)} X[j] --------------
// Verified R8 body. One wave per node; 16 edges / 4 independent 8B loads in
// flight. All __shfl exec-uniform (clamped source in tail) -- the R5 lesson.
__global__ void __launch_bounds__(256) gather_bf16(
    const unsigned short* __restrict__ Xbf, const int* __restrict__ startA,
    const int* __restrict__ endA, const int* __restrict__ csr,
    float* __restrict__ agg) {
    int tid = threadIdx.x;
    int wave = tid >> 6, lane = tid & 63;
    int node = blockIdx.x * 4 + wave;
    int sub = lane >> 4, fq = lane & 15;
    int j0 = startA[node], je = endA[node];
    float a0 = 0.f, a1 = 0.f, a2 = 0.f, a3 = 0.f;
    for (int jb = j0; jb < je; jb += 64) {          // je wave-uniform
        int idx = jb + lane;
        int p = csr[idx < je ? idx : (je - 1)];     // coalesced index batch
        int m = min(64, je - jb);                   // wave-uniform
        int b = 0;
        for (; b + 16 <= m; b += 16) {
            int i0 = __shfl(p, b + sub, 64);
            int i1 = __shfl(p, b + 4 + sub, 64);
            int i2 = __shfl(p, b + 8 + sub, 64);
            int i3 = __shfl(p, b + 12 + sub, 64);
            uint2 u0 = *(const uint2*)(Xbf + i0 * D + fq * 4);
            uint2 u1 = *(const uint2*)(Xbf + i1 * D + fq * 4);
            uint2 u2 = *(const uint2*)(Xbf + i2 * D + fq * 4);
            uint2 u3 = *(const uint2*)(Xbf + i3 * D + fq * 4);
            a0 += bflo(u0.x) + bflo(u1.x) + bflo(u2.x) + bflo(u3.x);
            a1 += bfhi(u0.x) + bfhi(u1.x) + bfhi(u2.x) + bfhi(u3.x);
            a2 += bflo(u0.y) + bflo(u1.y) + bflo(u2.y) + bflo(u3.y);
            a3 += bfhi(u0.y) + bfhi(u1.y) + bfhi(u2.y) + bfhi(u3.y);
        }
        for (; b < m; b += 4) {                     // uniform condition
            int sidx = b + sub;
            int scl = sidx < m ? sidx : (m - 1);    // active source lane
            int i0 = __shfl(p, scl, 64);            // executed by ALL lanes
            if (sidx < m) {                         // divergence only here
                uint2 u = *(const uint2*)(Xbf + i0 * D + fq * 4);
                a0 += bflo(u.x); a1 += bfhi(u.x);
                a2 += bflo(u.y); a3 += bfhi(u.y);
            }
        }
    }
#pragma unroll
    for (int mk = 16; mk <= 32; mk <<= 1) {
        a0 += __shfl_xor(a0, mk, 64);
        a1 += __shfl_xor(a1, mk, 64);
        a2 += __shfl_xor(a2, mk, 64);
        a3 += __shfl_xor(a3, mk, 64);
    }
    if (sub == 0) ((float4*)agg)[node * 16 + fq] = make_float4(a0, a1, a2, a3);
}

// ---------- Register-blocked dual GEMM (+ optional bf16 side-write) ---------
// Verified R8 body.
template<int RELU, int WBF>
__global__ void __launch_bounds__(256) dual_gemm(
    const float* __restrict__ X, const float* __restrict__ A,
    const float* __restrict__ Wr, const float* __restrict__ Wn,
    const float* __restrict__ bias, float* __restrict__ out,
    unsigned short* __restrict__ outBf) {
    __shared__ float sXT[D][D];
    __shared__ float sAT[D][D];
    __shared__ float sWr[D][D];
    __shared__ float sWn[D][D];

    int tid = threadIdx.x;
    int node0 = blockIdx.x * 64;

#pragma unroll
    for (int i = 0; i < 4; i++) {
        int idx = tid + 256 * i;
        ((float4*)sWr)[idx] = ((const float4*)Wr)[idx];
        ((float4*)sWn)[idx] = ((const float4*)Wn)[idx];
    }
    const float4* X4 = (const float4*)X;
    const float4* A4 = (const float4*)A;
    int nd = tid & 63;
    int gn = min(node0 + nd, N_NODES - 1);
#pragma unroll
    for (int pass = 0; pass < 4; pass++) {
        int kq = (tid >> 6) + pass * 4;
        float4 v = X4[gn * 16 + kq];
        float4 w = A4[gn * 16 + kq];
        sXT[kq * 4 + 0][nd] = v.x; sXT[kq * 4 + 1][nd] = v.y;
        sXT[kq * 4 + 2][nd] = v.z; sXT[kq * 4 + 3][nd] = v.w;
        sAT[kq * 4 + 0][nd] = w.x; sAT[kq * 4 + 1][nd] = w.y;
        sAT[kq * 4 + 2][nd] = w.z; sAT[kq * 4 + 3][nd] = w.w;
    }
    __syncthreads();

    int nq = tid >> 4;
    int cq = tid & 15;
    float4 b4 = ((const float4*)bias)[cq];
    float acc[4][4];
#pragma unroll
    for (int i = 0; i < 4; i++) {
        acc[i][0] = b4.x; acc[i][1] = b4.y; acc[i][2] = b4.z; acc[i][3] = b4.w;
    }

#pragma unroll 16
    for (int k = 0; k < D; k++) {
        float4 xv = *(const float4*)&sXT[k][nq * 4];
        float4 av = *(const float4*)&sAT[k][nq * 4];
        float4 wr = *(const float4*)&sWr[k][cq * 4];
        float4 wn = *(const float4*)&sWn[k][cq * 4];
        float xs[4] = {xv.x, xv.y, xv.z, xv.w};
        float as[4] = {av.x, av.y, av.z, av.w};
        float rs[4] = {wr.x, wr.y, wr.z, wr.w};
        float ns[4] = {wn.x, wn.y, wn.z, wn.w};
#pragma unroll
        for (int i = 0; i < 4; i++)
#pragma unroll
            for (int jj = 0; jj < 4; jj++) {
                acc[i][jj] = fmaf(xs[i], rs[jj], acc[i][jj]);
                acc[i][jj] = fmaf(as[i], ns[jj], acc[i][jj]);
            }
    }

    float4* out4 = (float4*)out;
#pragma unroll
    for (int i = 0; i < 4; i++) {
        int node = node0 + nq * 4 + i;
        if (node < N_NODES) {
            float4 r;
            r.x = acc[i][0]; r.y = acc[i][1]; r.z = acc[i][2]; r.w = acc[i][3];
            if (RELU) {
                r.x = fmaxf(r.x, 0.f); r.y = fmaxf(r.y, 0.f);
                r.z = fmaxf(r.z, 0.f); r.w = fmaxf(r.w, 0.f);
            }
            out4[node * 16 + cq] = r;
            if (WBF) {
                ushort4 rb;
                rb.x = f2bf(r.x); rb.y = f2bf(r.y);
                rb.z = f2bf(r.z); rb.w = f2bf(r.w);
                *(ushort4*)(outBf + node * D + cq * 4) = rb;
            }
        }
    }
}

// ---------- launch ----------------------------------------------------------
extern "C" void kernel_launch(void* const* d_in, const int* in_sizes, int n_in,
                              void* d_out, int out_size, void* d_ws, size_t ws_size,
                              hipStream_t stream) {
    const float* x   = (const float*)d_in[0];
    const int*   edg = (const int*)d_in[1];
    const float* W1r = (const float*)d_in[2];
    const float* W1n = (const float*)d_in[3];
    const float* b1  = (const float*)d_in[4];
    const float* W2r = (const float*)d_in[5];
    const float* W2n = (const float*)d_in[6];
    const float* b2  = (const float*)d_in[7];
    float* out = (float*)d_out;

    const int* src = edg;
    const int* dst = edg + N_EDGES;

    // ws (256 MiB available) — generous non-overlapping padded layout.
    int* W             = (int*)d_ws;
    int* cursorPad     = W;                         // 196*16 ints (counts)
    int* staged        = W + 4096;                  // NBUCKETS*BCAP
    int* csr           = staged + NBUCKETS * BCAP;  // NBUCKETS*BCAP
    int* startA        = csr + NBUCKETS * BCAP;
    int* endA          = startA + N_NODES;
    float* agg         = (float*)(endA + N_NODES);              // N*D f32
    unsigned short* xbf = (unsigned short*)(agg + (size_t)N_NODES * D);
    unsigned short* hbf = xbf + (size_t)N_NODES * D;
    float* h           = out;      // layer-1 fp32 activations in d_out

    hipMemsetAsync(cursorPad, 0, 196 * 16 * sizeof(int), stream);
    scatter_cast_kernel<<<SBLOCKS + CASTBLOCKS, 256, 0, stream>>>(
        src, dst, x, cursorPad, staged, xbf);
    csr_build_kernel<<<NBUCKETS, 256, 0, stream>>>(cursorPad, staged, csr,
                                                   startA, endA);

    const int GB = N_NODES / 4;          // 12500
    const int MB = (N_NODES + 63) / 64;  // 782

    gather_bf16<<<GB, 256, 0, stream>>>(xbf, startA, endA, csr, agg);
    dual_gemm<1, 1><<<MB, 256, 0, stream>>>(x, agg, W1r, W1n, b1, h, hbf);
    gather_bf16<<<GB, 256, 0, stream>>>(hbf, startA, endA, csr, agg);
    dual_gemm<0, 0><<<MB, 256, 0, stream>>>(h, agg, W2r, W2n, b2, out,
                                            (unsigned short*)0);
}

// Round 11
// 197.024 us; speedup vs baseline: 1.2570x; 1.0333x over previous
//
#include <hip/hip_runtime.h>

#define N_NODES 50000
#define N_EDGES 800000
#define D 64
#define NBUCKETS 196          // dst>>8, 0..195
#define BCAP 8192             // fixed bucket capacity (Poisson(4082), 5sigma<4400)
#define SBLOCKS 256           // scatter blocks
#define CHUNK (N_EDGES / SBLOCKS)   // 3125
#define CASTBLOCKS 3125       // N*D/4 ushort4 items / 256 threads

// bf16 helpers (RNE), bit-level.
__device__ __forceinline__ unsigned short f2bf(float f) {
    unsigned u = __float_as_uint(f);
    return (unsigned short)((u + 0x7fffu + ((u >> 16) & 1u)) >> 16);
}
__device__ __forceinline__ float bflo(unsigned u) {
    return __uint_as_float(u << 16);
}
__device__ __forceinline__ float bfhi(unsigned u) {
    return __uint_as_float(u & 0xffff0000u);
}

// ---------- Scatter into fixed-capacity buckets + fused x->bf16 cast --------
__global__ void __launch_bounds__(256) scatter_cast_kernel(
    const int* __restrict__ src, const int* __restrict__ dst,
    const float* __restrict__ X,
    int* __restrict__ cursorPad, int* __restrict__ staged,
    unsigned short* __restrict__ Xbf) {
    int t = threadIdx.x;
    if (blockIdx.x >= SBLOCKS) {
        int i = (blockIdx.x - SBLOCKS) * 256 + t;   // over N*D/4
        float4 v = ((const float4*)X)[i];
        ushort4 r;
        r.x = f2bf(v.x); r.y = f2bf(v.y); r.z = f2bf(v.z); r.w = f2bf(v.w);
        ((ushort4*)Xbf)[i] = r;
        return;
    }
    __shared__ int hist[256];
    __shared__ int curs[256];
    hist[t] = 0;
    __syncthreads();
    int lo = blockIdx.x * CHUNK, hi = lo + CHUNK;
    for (int i = lo + t; i < hi; i += 256)
        atomicAdd(&hist[dst[i] >> 8], 1);
    __syncthreads();
    if (hist[t] > 0)
        curs[t] = t * BCAP + atomicAdd(&cursorPad[t * 16], hist[t]);
    __syncthreads();
    for (int i = lo + t; i < hi; i += 256) {
        int d = dst[i];
        int b = d >> 8;
        int pos = atomicAdd(&curs[b], 1);
        staged[pos] = (src[i] << 8) | (d & 255);
    }
}

// ---------- Per-bucket CSR build (padded regions; LDS scan + cursors) -------
__global__ void __launch_bounds__(256) csr_build_kernel(
    const int* __restrict__ cursorPad, const int* __restrict__ staged,
    int* __restrict__ csr, int* __restrict__ startA, int* __restrict__ endA) {
    __shared__ int deg[256];
    __shared__ int sc[256];
    __shared__ int curs[256];
    int k = blockIdx.x;
    int t = threadIdx.x;
    int base = k * BCAP;
    int cnt  = cursorPad[k * 16];
    deg[t] = 0;
    __syncthreads();
    for (int i = t; i < cnt; i += 256)
        atomicAdd(&deg[staged[base + i] & 255], 1);
    __syncthreads();
    int v = deg[t];
    sc[t] = v;
    __syncthreads();
#pragma unroll
    for (int d = 1; d < 256; d <<= 1) {
        int u = (t >= d) ? sc[t - d] : 0;
        __syncthreads();
        sc[t] += u;
        __syncthreads();
    }
    int start = sc[t] - v;
    int node = k * 256 + t;
    if (node < N_NODES) {
        startA[node] = base + start;
        endA[node]   = base + start + v;
    }
    curs[t] = start;
    __syncthreads();
    for (int i = t; i < cnt; i += 256) {
        int e = staged[base + i];
        int pos = atomicAdd(&curs[e & 255], 1);
        csr[base + pos] = e >> 8;
    }
}

// ---------- Gather (bf16 rows -> bf16 agg) ----------------------------------
// Verified R8 body; only the final store changed to bf16.
__global__ void __launch_bounds__(256) gather_bf16(
    const unsigned short* __restrict__ Xbf, const int* __restrict__ startA,
    const int* __restrict__ endA, const int* __restrict__ csr,
    unsigned short* __restrict__ aggbf) {
    int tid = threadIdx.x;
    int wave = tid >> 6, lane = tid & 63;
    int node = blockIdx.x * 4 + wave;
    int sub = lane >> 4, fq = lane & 15;
    int j0 = startA[node], je = endA[node];
    float a0 = 0.f, a1 = 0.f, a2 = 0.f, a3 = 0.f;
    for (int jb = j0; jb < je; jb += 64) {          // je wave-uniform
        int idx = jb + lane;
        int p = csr[idx < je ? idx : (je - 1)];     // coalesced index batch
        int m = min(64, je - jb);                   // wave-uniform
        int b = 0;
        for (; b + 16 <= m; b += 16) {
            int i0 = __shfl(p, b + sub, 64);
            int i1 = __shfl(p, b + 4 + sub, 64);
            int i2 = __shfl(p, b + 8 + sub, 64);
            int i3 = __shfl(p, b + 12 + sub, 64);
            uint2 u0 = *(const uint2*)(Xbf + i0 * D + fq * 4);
            uint2 u1 = *(const uint2*)(Xbf + i1 * D + fq * 4);
            uint2 u2 = *(const uint2*)(Xbf + i2 * D + fq * 4);
            uint2 u3 = *(const uint2*)(Xbf + i3 * D + fq * 4);
            a0 += bflo(u0.x) + bflo(u1.x) + bflo(u2.x) + bflo(u3.x);
            a1 += bfhi(u0.x) + bfhi(u1.x) + bfhi(u2.x) + bfhi(u3.x);
            a2 += bflo(u0.y) + bflo(u1.y) + bflo(u2.y) + bflo(u3.y);
            a3 += bfhi(u0.y) + bfhi(u1.y) + bfhi(u2.y) + bfhi(u3.y);
        }
        for (; b < m; b += 4) {                     // uniform condition
            int sidx = b + sub;
            int scl = sidx < m ? sidx : (m - 1);    // active source lane
            int i0 = __shfl(p, scl, 64);            // executed by ALL lanes
            if (sidx < m) {                         // divergence only here
                uint2 u = *(const uint2*)(Xbf + i0 * D + fq * 4);
                a0 += bflo(u.x); a1 += bfhi(u.x);
                a2 += bflo(u.y); a3 += bfhi(u.y);
            }
        }
    }
#pragma unroll
    for (int mk = 16; mk <= 32; mk <<= 1) {
        a0 += __shfl_xor(a0, mk, 64);
        a1 += __shfl_xor(a1, mk, 64);
        a2 += __shfl_xor(a2, mk, 64);
        a3 += __shfl_xor(a3, mk, 64);
    }
    if (sub == 0) {
        ushort4 r;
        r.x = f2bf(a0); r.y = f2bf(a1); r.z = f2bf(a2); r.w = f2bf(a3);
        *(ushort4*)(aggbf + (size_t)node * D + fq * 4) = r;
    }
}

// ---------- Register-blocked dual GEMM --------------------------------------
// A staged from bf16; X staged from fp32 (XBF=0) or bf16 (XBF=1).
// WOUT: write fp32 out; WBF: write bf16 copy.
template<int RELU, int WOUT, int WBF, int XBF>
__global__ void __launch_bounds__(256) dual_gemm(
    const float* __restrict__ Xf, const unsigned short* __restrict__ Xb,
    const unsigned short* __restrict__ Abf,
    const float* __restrict__ Wr, const float* __restrict__ Wn,
    const float* __restrict__ bias, float* __restrict__ out,
    unsigned short* __restrict__ outBf) {
    __shared__ float sXT[D][D];
    __shared__ float sAT[D][D];
    __shared__ float sWr[D][D];
    __shared__ float sWn[D][D];

    int tid = threadIdx.x;
    int node0 = blockIdx.x * 64;

#pragma unroll
    for (int i = 0; i < 4; i++) {
        int idx = tid + 256 * i;
        ((float4*)sWr)[idx] = ((const float4*)Wr)[idx];
        ((float4*)sWn)[idx] = ((const float4*)Wn)[idx];
    }
    int nd = tid & 63;
    int gn = min(node0 + nd, N_NODES - 1);
    // A (and optionally X) from bf16: 2 passes x uint4 (8 bf16 k's each).
#pragma unroll
    for (int pass = 0; pass < 2; pass++) {
        int kg = (tid >> 6) + pass * 4;       // 0..7
        int k0 = kg * 8;
        uint4 ua = *(const uint4*)(Abf + (size_t)gn * D + k0);
        sAT[k0 + 0][nd] = bflo(ua.x); sAT[k0 + 1][nd] = bfhi(ua.x);
        sAT[k0 + 2][nd] = bflo(ua.y); sAT[k0 + 3][nd] = bfhi(ua.y);
        sAT[k0 + 4][nd] = bflo(ua.z); sAT[k0 + 5][nd] = bfhi(ua.z);
        sAT[k0 + 6][nd] = bflo(ua.w); sAT[k0 + 7][nd] = bfhi(ua.w);
        if (XBF) {
            uint4 ux = *(const uint4*)(Xb + (size_t)gn * D + k0);
            sXT[k0 + 0][nd] = bflo(ux.x); sXT[k0 + 1][nd] = bfhi(ux.x);
            sXT[k0 + 2][nd] = bflo(ux.y); sXT[k0 + 3][nd] = bfhi(ux.y);
            sXT[k0 + 4][nd] = bflo(ux.z); sXT[k0 + 5][nd] = bfhi(ux.z);
            sXT[k0 + 6][nd] = bflo(ux.w); sXT[k0 + 7][nd] = bfhi(ux.w);
        }
    }
    if (!XBF) {
        const float4* X4 = (const float4*)Xf;
#pragma unroll
        for (int pass = 0; pass < 4; pass++) {
            int kq = (tid >> 6) + pass * 4;
            float4 v = X4[gn * 16 + kq];
            sXT[kq * 4 + 0][nd] = v.x; sXT[kq * 4 + 1][nd] = v.y;
            sXT[kq * 4 + 2][nd] = v.z; sXT[kq * 4 + 3][nd] = v.w;
        }
    }
    __syncthreads();

    int nq = tid >> 4;
    int cq = tid & 15;
    float4 b4 = ((const float4*)bias)[cq];
    float acc[4][4];
#pragma unroll
    for (int i = 0; i < 4; i++) {
        acc[i][0] = b4.x; acc[i][1] = b4.y; acc[i][2] = b4.z; acc[i][3] = b4.w;
    }

#pragma unroll 16
    for (int k = 0; k < D; k++) {
        float4 xv = *(const float4*)&sXT[k][nq * 4];
        float4 av = *(const float4*)&sAT[k][nq * 4];
        float4 wr = *(const float4*)&sWr[k][cq * 4];
        float4 wn = *(const float4*)&sWn[k][cq * 4];
        float xs[4] = {xv.x, xv.y, xv.z, xv.w};
        float as[4] = {av.x, av.y, av.z, av.w};
        float rs[4] = {wr.x, wr.y, wr.z, wr.w};
        float ns[4] = {wn.x, wn.y, wn.z, wn.w};
#pragma unroll
        for (int i = 0; i < 4; i++)
#pragma unroll
            for (int jj = 0; jj < 4; jj++) {
                acc[i][jj] = fmaf(xs[i], rs[jj], acc[i][jj]);
                acc[i][jj] = fmaf(as[i], ns[jj], acc[i][jj]);
            }
    }

    float4* out4 = (float4*)out;
#pragma unroll
    for (int i = 0; i < 4; i++) {
        int node = node0 + nq * 4 + i;
        if (node < N_NODES) {
            float4 r;
            r.x = acc[i][0]; r.y = acc[i][1]; r.z = acc[i][2]; r.w = acc[i][3];
            if (RELU) {
                r.x = fmaxf(r.x, 0.f); r.y = fmaxf(r.y, 0.f);
                r.z = fmaxf(r.z, 0.f); r.w = fmaxf(r.w, 0.f);
            }
            if (WOUT) out4[node * 16 + cq] = r;
            if (WBF) {
                ushort4 rb;
                rb.x = f2bf(r.x); rb.y = f2bf(r.y);
                rb.z = f2bf(r.z); rb.w = f2bf(r.w);
                *(ushort4*)(outBf + (size_t)node * D + cq * 4) = rb;
            }
        }
    }
}

// ---------- launch ----------------------------------------------------------
extern "C" void kernel_launch(void* const* d_in, const int* in_sizes, int n_in,
                              void* d_out, int out_size, void* d_ws, size_t ws_size,
                              hipStream_t stream) {
    const float* x   = (const float*)d_in[0];
    const int*   edg = (const int*)d_in[1];
    const float* W1r = (const float*)d_in[2];
    const float* W1n = (const float*)d_in[3];
    const float* b1  = (const float*)d_in[4];
    const float* W2r = (const float*)d_in[5];
    const float* W2n = (const float*)d_in[6];
    const float* b2  = (const float*)d_in[7];
    float* out = (float*)d_out;

    const int* src = edg;
    const int* dst = edg + N_EDGES;

    // ws (256 MiB available) — generous non-overlapping padded layout.
    int* W              = (int*)d_ws;
    int* cursorPad      = W;                         // 196*16 ints
    int* staged         = W + 4096;                  // NBUCKETS*BCAP
    int* csr            = staged + NBUCKETS * BCAP;  // NBUCKETS*BCAP
    int* startA         = csr + NBUCKETS * BCAP;
    int* endA           = startA + N_NODES;
    unsigned short* xbf = (unsigned short*)(endA + N_NODES);   // N*D bf16
    unsigned short* hbf = xbf + (size_t)N_NODES * D;           // N*D bf16
    unsigned short* agb = hbf + (size_t)N_NODES * D;           // N*D bf16

    hipMemsetAsync(cursorPad, 0, 196 * 16 * sizeof(int), stream);
    scatter_cast_kernel<<<SBLOCKS + CASTBLOCKS, 256, 0, stream>>>(
        src, dst, x, cursorPad, staged, xbf);
    csr_build_kernel<<<NBUCKETS, 256, 0, stream>>>(cursorPad, staged, csr,
                                                   startA, endA);

    const int GB = N_NODES / 4;          // 12500
    const int MB = (N_NODES + 63) / 64;  // 782

    // Layer 1: X from fp32 x, A from bf16 agg; write ONLY hbf (no fp32 h).
    gather_bf16<<<GB, 256, 0, stream>>>(xbf, startA, endA, csr, agb);
    dual_gemm<1, 0, 1, 0><<<MB, 256, 0, stream>>>(x, (unsigned short*)0, agb,
                                                  W1r, W1n, b1, out, hbf);
    // Layer 2: X from bf16 hbf, A from bf16 agg; write fp32 out.
    gather_bf16<<<GB, 256, 0, stream>>>(hbf, startA, endA, csr, agb);
    dual_gemm<0, 1, 0, 1><<<MB, 256, 0, stream>>>((const float*)0, hbf, agb,
                                                  W2r, W2n, b2, out,
                                                  (unsigned short*)0);
}